// Round 2
// baseline (1431.604 us; speedup 1.0000x reference)
//
#include <hip/hip_runtime.h>
#include <cstdint>
#include <cstddef>

typedef unsigned short u16;
typedef unsigned int u32;
typedef __attribute__((ext_vector_type(8))) _Float16 half8;   // 8 x f16 MFMA frag
typedef __attribute__((ext_vector_type(4))) float floatx4;    // MFMA acc
typedef __attribute__((ext_vector_type(4))) u16 u16x4;
typedef __attribute__((ext_vector_type(8))) u16 u16x8;

#define H_ 16
#define S_ 4096
#define D_ 64
#define BM 64
#define BN 64
#define PAD 68                 // LDS row stride in u16: 136B -> 8B aligned, conflict-free b64 reads
#define MBW (S_ / 32)          // 128 mask words per row

__device__ __forceinline__ u16 f2h(float x) {
  union { _Float16 h; u16 u; } c;
  c.h = (_Float16)x;           // v_cvt_f16_f32, RNE
  return c.u;
}

__device__ __forceinline__ void st_lds8(u16* p, u16x8 v) {
  union { u16x8 w; u16x4 h[2]; } u; u.w = v;
  *(u16x4*)p = u.h[0];
  *(u16x4*)(p + 4) = u.h[1];
}

__device__ __forceinline__ half8 ld_frag(const u16* p) {
  union { half8 v; u16x4 h[2]; } u;
  u.h[0] = *(const u16x4*)p;
  u.h[1] = *(const u16x4*)(p + 4);
  return u.v;
}

// stage a 64x64 f16 tile (global row-major, stride gstride) into LDS [64][PAD]
__device__ __forceinline__ void stage_tile(const u16* __restrict__ g, int gstride,
                                           u16* lds, int tid) {
  int r = tid >> 2, c0 = (tid & 3) * 16;
  const u16* src = g + (size_t)r * gstride + c0;
  u16x8 a = *(const u16x8*)(src);
  u16x8 b = *(const u16x8*)(src + 8);
  u16* d = lds + r * PAD + c0;
  st_lds8(d, a);
  st_lds8(d + 8, b);
}

// ---- prep: fp32 Q,K -> f16 copies ----
__global__ void prep_qk(const float* __restrict__ q, const float* __restrict__ kk,
                        u16* __restrict__ qb, u16* __restrict__ kb) {
  const size_t N = (size_t)H_ * S_ * D_;
  size_t idx = ((size_t)blockIdx.x * 256 + threadIdx.x) * 8;
  const float* src;
  u16* dst;
  if (idx < N) { src = q + idx; dst = qb + idx; }
  else         { src = kk + (idx - N); dst = kb + (idx - N); }
  float4 f0 = *(const float4*)src;
  float4 f1 = *(const float4*)(src + 4);
  u16x8 o;
  o[0] = f2h(f0.x); o[1] = f2h(f0.y); o[2] = f2h(f0.z); o[3] = f2h(f0.w);
  o[4] = f2h(f1.x); o[5] = f2h(f1.y); o[6] = f2h(f1.z); o[7] = f2h(f1.w);
  *(u16x8*)dst = o;
}

// ---- prep: fp32 V [H][S][D] -> f16 V^T [H][D][S] ----
__global__ void prep_vt(const float* __restrict__ v, u16* __restrict__ vt) {
  __shared__ float tile[64][65];
  int h = blockIdx.y, s0 = blockIdx.x * 64;
  int t = threadIdx.x;
  int r = t >> 2, c0 = (t & 3) * 16;
  const float* src = v + ((size_t)(h * S_ + s0 + r)) * D_ + c0;
  #pragma unroll
  for (int i = 0; i < 16; i += 4) {
    float4 f = *(const float4*)(src + i);
    tile[r][c0 + i + 0] = f.x; tile[r][c0 + i + 1] = f.y;
    tile[r][c0 + i + 2] = f.z; tile[r][c0 + i + 3] = f.w;
  }
  __syncthreads();
  u16* dst = vt + ((size_t)(h * D_ + r)) * S_ + s0 + c0;
  u16x8 o0, o1;
  #pragma unroll
  for (int i = 0; i < 8; i++) o0[i] = f2h(tile[c0 + i][r]);
  #pragma unroll
  for (int i = 0; i < 8; i++) o1[i] = f2h(tile[c0 + 8 + i][r]);
  *(u16x8*)dst = o0;
  *(u16x8*)(dst + 8) = o1;
}

// ---- prep: int32 mask [S][S] -> bitmask [S][S/32] ----
__global__ void prep_mask(const int* __restrict__ mask, u32* __restrict__ mb) {
  size_t widx = (size_t)blockIdx.x * 256 + threadIdx.x;
  const int* src = mask + widx * 32;
  u32 bits = 0;
  #pragma unroll
  for (int i = 0; i < 8; i++) {
    int4 m4 = *(const int4*)(src + i * 4);
    bits |= (m4.x != 0 ? 1u : 0u) << (i * 4 + 0);
    bits |= (m4.y != 0 ? 1u : 0u) << (i * 4 + 1);
    bits |= (m4.z != 0 ? 1u : 0u) << (i * 4 + 2);
    bits |= (m4.w != 0 ? 1u : 0u) << (i * 4 + 3);
  }
  mb[widx] = bits;
}

// ---- fused attention: pass1 row-sums (no max needed: |s| < ~60), pass2 write attn + PV ----
__global__ __launch_bounds__(256, 4)
void attn_fused(const u16* __restrict__ qb, const u16* __restrict__ kb,
                const u16* __restrict__ vt, const u32* __restrict__ mb,
                float* __restrict__ out, float* __restrict__ attn) {
  __shared__ u16 Qs[BM * PAD];
  __shared__ u16 Ks[BN * PAD];
  __shared__ u16 Vts[D_ * PAD];
  __shared__ u16 Ps[BM * PAD];
  __shared__ float Linv[BM];

  const int h = blockIdx.y;
  const int row0 = blockIdx.x * BM;
  const int tid = threadIdx.x;
  const int wave = tid >> 6;
  const int lane = tid & 63;
  const int lrow = lane & 15;
  const int quad = lane >> 4;

  stage_tile(qb + ((size_t)(h * S_ + row0)) * D_, D_, Qs, tid);

  const u16* kbase = kb + (size_t)h * S_ * D_;
  const u16* vbase = vt + (size_t)h * D_ * S_;

  const int arow_off = (wave * 16 + lrow) * PAD;  // A-frag row base (m = lane&15)
  const int k0 = quad * 8;                        // A/B frag k offset
  const int lr0 = wave * 16 + quad * 4;           // C-layout row base (+r)

  // ---------- pass 1: row sums of mask-gated exp(scores) ----------
  float rsum[4] = {0.f, 0.f, 0.f, 0.f};
  for (int j0 = 0; j0 < S_; j0 += BN) {
    __syncthreads();
    stage_tile(kbase + (size_t)j0 * D_, D_, Ks, tid);
    __syncthreads();
    half8 a0 = ld_frag(&Qs[arow_off + k0]);
    half8 a1 = ld_frag(&Qs[arow_off + 32 + k0]);
    u32 mwx[4], mwy[4];
    #pragma unroll
    for (int r = 0; r < 4; r++) {
      const u32* mp = mb + (size_t)(row0 + lr0 + r) * MBW + (j0 >> 5);
      uint2 w = *(const uint2*)mp;
      mwx[r] = w.x; mwy[r] = w.y;
    }
    #pragma unroll
    for (int c = 0; c < 4; c++) {
      half8 b0 = ld_frag(&Ks[(c * 16 + lrow) * PAD + k0]);
      half8 b1 = ld_frag(&Ks[(c * 16 + lrow) * PAD + 32 + k0]);
      floatx4 sc = {0.f, 0.f, 0.f, 0.f};
      sc = __builtin_amdgcn_mfma_f32_16x16x32_f16(a0, b0, sc, 0, 0, 0);
      sc = __builtin_amdgcn_mfma_f32_16x16x32_f16(a1, b1, sc, 0, 0, 0);
      const int sh = (c & 1) * 16 + lrow;
      #pragma unroll
      for (int r = 0; r < 4; r++) {
        u32 w = (c < 2) ? mwx[r] : mwy[r];
        rsum[r] += ((w >> sh) & 1u) ? __expf(sc[r]) : 0.f;
      }
    }
  }
  #pragma unroll
  for (int r = 0; r < 4; r++) {
    float s = rsum[r];
    s += __shfl_xor(s, 1);
    s += __shfl_xor(s, 2);
    s += __shfl_xor(s, 4);
    s += __shfl_xor(s, 8);
    if (lrow == 0) Linv[lr0 + r] = 1.0f / s;
  }
  __syncthreads();
  float linv[4];
  #pragma unroll
  for (int r = 0; r < 4; r++) linv[r] = Linv[lr0 + r];

  // ---------- pass 2: recompute scores, write attn, accumulate PV ----------
  floatx4 acc[4];
  #pragma unroll
  for (int c = 0; c < 4; c++) acc[c] = (floatx4){0.f, 0.f, 0.f, 0.f};

  float* attnh = attn + (size_t)h * S_ * S_;

  for (int j0 = 0; j0 < S_; j0 += BN) {
    __syncthreads();
    stage_tile(kbase + (size_t)j0 * D_, D_, Ks, tid);
    stage_tile(vbase + j0, S_, Vts, tid);
    __syncthreads();
    half8 a0 = ld_frag(&Qs[arow_off + k0]);
    half8 a1 = ld_frag(&Qs[arow_off + 32 + k0]);
    u32 mwx[4], mwy[4];
    #pragma unroll
    for (int r = 0; r < 4; r++) {
      const u32* mp = mb + (size_t)(row0 + lr0 + r) * MBW + (j0 >> 5);
      uint2 w = *(const uint2*)mp;
      mwx[r] = w.x; mwy[r] = w.y;
    }
    #pragma unroll
    for (int c = 0; c < 4; c++) {
      half8 b0 = ld_frag(&Ks[(c * 16 + lrow) * PAD + k0]);
      half8 b1 = ld_frag(&Ks[(c * 16 + lrow) * PAD + 32 + k0]);
      floatx4 sc = {0.f, 0.f, 0.f, 0.f};
      sc = __builtin_amdgcn_mfma_f32_16x16x32_f16(a0, b0, sc, 0, 0, 0);
      sc = __builtin_amdgcn_mfma_f32_16x16x32_f16(a1, b1, sc, 0, 0, 0);
      const int sh = (c & 1) * 16 + lrow;
      const int ccol = c * 16 + lrow;
      #pragma unroll
      for (int r = 0; r < 4; r++) {
        u32 w = (c < 2) ? mwx[r] : mwy[r];
        float p = ((w >> sh) & 1u) ? __expf(sc[r]) * linv[r] : 0.f;
        __builtin_nontemporal_store(p, &attnh[(size_t)(row0 + lr0 + r) * S_ + j0 + ccol]);
        Ps[(lr0 + r) * PAD + ccol] = f2h(p);
      }
    }
    __syncthreads();
    half8 p0 = ld_frag(&Ps[arow_off + k0]);
    half8 p1 = ld_frag(&Ps[arow_off + 32 + k0]);
    #pragma unroll
    for (int c = 0; c < 4; c++) {
      half8 v0 = ld_frag(&Vts[(c * 16 + lrow) * PAD + k0]);
      half8 v1 = ld_frag(&Vts[(c * 16 + lrow) * PAD + 32 + k0]);
      acc[c] = __builtin_amdgcn_mfma_f32_16x16x32_f16(p0, v0, acc[c], 0, 0, 0);
      acc[c] = __builtin_amdgcn_mfma_f32_16x16x32_f16(p1, v1, acc[c], 0, 0, 0);
    }
  }

  #pragma unroll
  for (int c = 0; c < 4; c++) {
    #pragma unroll
    for (int r = 0; r < 4; r++) {
      out[((size_t)(h * S_ + row0 + lr0 + r)) * D_ + c * 16 + lrow] = acc[c][r];
    }
  }
}

extern "C" void kernel_launch(void* const* d_in, const int* in_sizes, int n_in,
                              void* d_out, int out_size, void* d_ws, size_t ws_size,
                              hipStream_t stream) {
  const float* q = (const float*)d_in[0];
  const float* k = (const float*)d_in[1];
  const float* v = (const float*)d_in[2];
  const int* mask = (const int*)d_in[3];
  float* out = (float*)d_out;
  float* attn = out + (size_t)H_ * S_ * D_;

  const size_t N = (size_t)H_ * S_ * D_;   // 4,194,304 elements per tensor
  u16* qb = (u16*)d_ws;                    // f16 Q [H][S][D]
  u16* kb = qb + N;                        // f16 K [H][S][D]
  u16* vt = kb + N;                        // f16 V^T [H][D][S]
  u32* mb = (u32*)(vt + N);                // bitmask [S][S/32] (2 MB)

  prep_qk<<<dim3((unsigned)(2 * N / (256 * 8))), 256, 0, stream>>>(q, k, qb, kb);
  prep_vt<<<dim3(S_ / 64, H_), 256, 0, stream>>>(v, vt);
  prep_mask<<<dim3((unsigned)(((size_t)S_ * S_ / 32) / 256)), 256, 0, stream>>>(mask, mb);
  attn_fused<<<dim3(S_ / BM, H_), 256, 0, stream>>>(qb, kb, vt, mb, out, attn);
}